// Round 1
// baseline (500.539 us; speedup 1.0000x reference)
//
#include <hip/hip_runtime.h>
#include <stdint.h>

// SimpleMarkovModel: 2-state Markov chain, 200000 emitters x 500 frames.
// Correctness hinges on bit-exact JAX Threefry-2x32 reproduction.
// This version implements the *partitionable* (modern default) JAX PRNG:
//   subkey[f]      = threefry2x32((0,42), (0, f))            (both words)
//   bits[f][p]     = hi ^ lo of threefry2x32(subkey[f], (0, p)),  p = 2n+c
//   u = (bits >> 9) * 2^-23  ->  (u < p1[c]) <=> (bits>>9) < ceil(p1[c]*2^23)

__device__ __forceinline__ void tf2x32(uint32_t k0, uint32_t k1,
                                       uint32_t x0, uint32_t x1,
                                       uint32_t& o0, uint32_t& o1) {
  const uint32_t k2 = k0 ^ k1 ^ 0x1BD11BDAu;
  x0 += k0; x1 += k1;
#define TF_R(d) { x0 += x1; x1 = (x1 << (d)) | (x1 >> (32 - (d))); x1 ^= x0; }
  TF_R(13) TF_R(15) TF_R(26) TF_R(6)
  x0 += k1; x1 += k2 + 1u;
  TF_R(17) TF_R(29) TF_R(16) TF_R(24)
  x0 += k2; x1 += k0 + 2u;
  TF_R(13) TF_R(15) TF_R(26) TF_R(6)
  x0 += k0; x1 += k1 + 3u;
  TF_R(17) TF_R(29) TF_R(16) TF_R(24)
  x0 += k1; x1 += k2 + 4u;
  TF_R(13) TF_R(15) TF_R(26) TF_R(6)
  x0 += k2; x1 += k0 + 5u;
#undef TF_R
  o0 = x0; o1 = x1;
}

__global__ void markov_kernel(const float* __restrict__ initial,
                              const float* __restrict__ transition,
                              const float* __restrict__ tmat,
                              float* __restrict__ out,
                              int N, int nf) {
  // Per-block: compute the 500 split subkeys into LDS (partitionable split:
  // keys[f] = threefry2x32(master=(0,42), x=(0,f)), both output words kept).
  extern __shared__ uint32_t kf[];  // kf[2f] = k0, kf[2f+1] = k1
  for (int f = threadIdx.x; f < nf; f += blockDim.x) {
    uint32_t a, b;
    tf2x32(0u, 42u, 0u, (uint32_t)f, a, b);
    kf[2 * f] = a;
    kf[2 * f + 1] = b;
  }
  __syncthreads();

  const int n = blockIdx.x * blockDim.x + threadIdx.x;
  if (n >= N) return;

  // Integer thresholds: u < p  <=>  (bits>>9) < ceil(p * 2^23).
  // p*2^23 is exact in f32 (mantissa unchanged, exponent shift), ceilf exact.
  const float p10 = transition[1];   // transition[0][1] = 0.5
  const float p11 = transition[3];   // transition[1][1] = 0.1
  const uint32_t thr0 = (uint32_t)ceilf(p10 * 8388608.0f);
  const uint32_t thr1 = (uint32_t)ceilf(p11 * 8388608.0f);

  // transition_matrix rows are one-hot (identity / swap); derive swap flags.
  const int sw0 = (tmat[1] != 0.0f) ? 1 : 0;   // m[0][0][1]
  const int sw1 = (tmat[5] != 0.0f) ? 1 : 0;   // m[1][0][1]

  // state index: initial[n] = [on, ~on]; s = 0 means state (1,0) ("on").
  int s = (initial[2 * n] != 0.0f) ? 0 : 1;

  const uint32_t pa = (uint32_t)(2 * n);   // flat pos of u[n][0]
  const uint32_t pb = pa + 1u;             // flat pos of u[n][1]

  float* op = out + n;
  for (int f = 0; f < nf; ++f) {
    const uint32_t k0 = kf[2 * f];
    const uint32_t k1 = kf[2 * f + 1];
    uint32_t a0, a1, b0, b1;
    tf2x32(k0, k1, 0u, pa, a0, a1);   // ILP: two independent ciphers
    tf2x32(k0, k1, 0u, pb, b0, b1);
    const int A0 = (((a0 ^ a1) >> 9) < thr0) ? 1 : 0;
    const int A1 = (((b0 ^ b1) >> 9) < thr1) ? 1 : 0;
    const int t = (s == 0) ? A0 : A1;
    s ^= t ? sw1 : sw0;
    op[(size_t)f * (size_t)N] = (s == 0) ? 1.0f : 0.0f;
  }
}

extern "C" void kernel_launch(void* const* d_in, const int* in_sizes, int n_in,
                              void* d_out, int out_size, void* d_ws, size_t ws_size,
                              hipStream_t stream) {
  const float* initial    = (const float*)d_in[0];
  const float* transition = (const float*)d_in[1];
  const float* tmat       = (const float*)d_in[2];
  float* out = (float*)d_out;

  const int N  = in_sizes[0] / 2;          // 200000 emitters
  const int nf = (N > 0) ? (out_size / N)  // 500 frames
                         : 0;
  if (N <= 0 || nf <= 0) return;

  const int block = 64;
  const int grid = (N + block - 1) / block;   // 3125 exactly for N=200000
  const size_t shmem = (size_t)(2 * nf) * sizeof(uint32_t);
  hipLaunchKernelGGL(markov_kernel, dim3(grid), dim3(block), shmem, stream,
                     initial, transition, tmat, out, N, nf);
}

// Round 2
// 281.407 us; speedup vs baseline: 1.7787x; 1.7787x over previous
//
#include <hip/hip_runtime.h>
#include <stdint.h>

// SimpleMarkovModel: 2-state Markov chain, 200000 emitters x 500 frames.
// Bit-exact JAX partitionable Threefry-2x32 (verified round 1, absmax 0).
//
// Key algebraic reduction vs round 1: the reference draws u[n][0..1] but only
// consumes u[n][s] (state one-hot -> t = A[s]), and s is known BEFORE the
// draw. So each emitter-frame needs exactly ONE threefry eval with counter
// x1 = 2n + s and threshold thr[s]. Halves the cipher work.
//
// Each thread owns TWO emitters (t and t+T) -> 2 independent cipher chains
// for ILP; stores remain fully coalesced (two contiguous runs per frame).

#define ROTL32(x, d) __builtin_rotateleft32((x), (d))

__device__ __forceinline__ void tf2x32(uint32_t k0, uint32_t k1,
                                       uint32_t x0, uint32_t x1,
                                       uint32_t& o0, uint32_t& o1) {
  const uint32_t k2 = k0 ^ k1 ^ 0x1BD11BDAu;
  x0 += k0; x1 += k1;
#define TF_R(d) { x0 += x1; x1 = ROTL32(x1, d) ^ x0; }
  TF_R(13) TF_R(15) TF_R(26) TF_R(6)
  x0 += k1; x1 += k2 + 1u;
  TF_R(17) TF_R(29) TF_R(16) TF_R(24)
  x0 += k2; x1 += k0 + 2u;
  TF_R(13) TF_R(15) TF_R(26) TF_R(6)
  x0 += k0; x1 += k1 + 3u;
  TF_R(17) TF_R(29) TF_R(16) TF_R(24)
  x0 += k1; x1 += k2 + 4u;
  TF_R(13) TF_R(15) TF_R(26) TF_R(6)
  x0 += k2; x1 += k0 + 5u;
#undef TF_R
  o0 = x0; o1 = x1;
}

// NCH = 1 or 2 chains. Dual-chain rounds interleaved for ILP; key-schedule
// constants shared across chains. kf has nf+1 entries (padded) so the
// next-frame prefetch never branches.
template <int NCH>
__device__ __forceinline__ void frames_loop(
    const uint2* __restrict__ kf, int nf, int N,
    uint32_t base0, uint32_t base1, int s0, int s1,
    uint32_t thr0, uint32_t thr1, int sw0, int sw1,
    float* __restrict__ o0, float* __restrict__ o1) {
  uint2 ck = kf[0];
  for (int f = 0; f < nf; ++f) {
    const uint32_t k0 = ck.x, k1 = ck.y;
    ck = kf[f + 1];  // prefetch next frame's subkey (padded at f == nf-1)
    const uint32_t k2 = k0 ^ k1 ^ 0x1BD11BDAu;
    const uint32_t c1 = k2 + 1u, c2 = k0 + 2u, c3 = k1 + 3u,
                   c4 = k2 + 4u, c5 = k0 + 5u;

    const uint32_t ta_thr = (s0 != 0) ? thr1 : thr0;
    const uint32_t tb_thr = (s1 != 0) ? thr1 : thr0;

    uint32_t xa0 = k0, xa1 = base0 + (uint32_t)s0 + k1;
    uint32_t xb0 = k0, xb1 = base1 + (uint32_t)s1 + k1;

#define RND(d)                                             \
  { xa0 += xa1; xa1 = ROTL32(xa1, (d)) ^ xa0;              \
    if (NCH == 2) { xb0 += xb1; xb1 = ROTL32(xb1, (d)) ^ xb0; } }
#define INJ(ia, ib)                                        \
  { xa0 += (ia); xa1 += (ib);                              \
    if (NCH == 2) { xb0 += (ia); xb1 += (ib); } }

    RND(13) RND(15) RND(26) RND(6)
    INJ(k1, c1)
    RND(17) RND(29) RND(16) RND(24)
    INJ(k2, c2)
    RND(13) RND(15) RND(26) RND(6)
    INJ(k0, c3)
    RND(17) RND(29) RND(16) RND(24)
    INJ(k1, c4)
    RND(13) RND(15) RND(26) RND(6)
    INJ(k2, c5)
#undef RND
#undef INJ

    const int ta = (((xa0 ^ xa1) >> 9) < ta_thr) ? 1 : 0;
    s0 ^= ta ? sw1 : sw0;
    *o0 = (s0 == 0) ? 1.0f : 0.0f;
    o0 += N;
    if (NCH == 2) {
      const int tb = (((xb0 ^ xb1) >> 9) < tb_thr) ? 1 : 0;
      s1 ^= tb ? sw1 : sw0;
      *o1 = (s1 == 0) ? 1.0f : 0.0f;
      o1 += N;
    }
  }
}

__global__ __launch_bounds__(256) void markov_kernel(
    const float* __restrict__ initial, const float* __restrict__ transition,
    const float* __restrict__ tmat, float* __restrict__ out,
    int N, int nf, int T) {
  // Per-block: the nf split subkeys into LDS, +1 zero pad for prefetch.
  extern __shared__ uint2 kf[];
  for (int f = threadIdx.x; f <= nf; f += blockDim.x) {
    uint2 k = make_uint2(0u, 0u);
    if (f < nf) {
      uint32_t a, b;
      tf2x32(0u, 42u, 0u, (uint32_t)f, a, b);
      k = make_uint2(a, b);
    }
    kf[f] = k;
  }
  __syncthreads();

  const int t = blockIdx.x * blockDim.x + threadIdx.x;
  if (t >= N) return;

  // u < p  <=>  (bits>>9) < ceil(p * 2^23)   (exact; p*2^23 exact in f32)
  const uint32_t thr0 = (uint32_t)ceilf(transition[1] * 8388608.0f);
  const uint32_t thr1 = (uint32_t)ceilf(transition[3] * 8388608.0f);
  const int sw0 = (tmat[1] != 0.0f) ? 1 : 0;  // matrix 0 swaps?
  const int sw1 = (tmat[5] != 0.0f) ? 1 : 0;  // matrix 1 swaps?

  const int n0 = t;
  const int n1 = t + T;
  const int s0 = (initial[2 * n0] != 0.0f) ? 0 : 1;

  if (n1 < N) {
    const int s1 = (initial[2 * n1] != 0.0f) ? 0 : 1;
    frames_loop<2>(kf, nf, N, (uint32_t)(2 * n0), (uint32_t)(2 * n1), s0, s1,
                   thr0, thr1, sw0, sw1, out + n0, out + n1);
  } else {
    frames_loop<1>(kf, nf, N, (uint32_t)(2 * n0), 0u, s0, 0,
                   thr0, thr1, sw0, sw1, out + n0, out + n0);
  }
}

extern "C" void kernel_launch(void* const* d_in, const int* in_sizes, int n_in,
                              void* d_out, int out_size, void* d_ws, size_t ws_size,
                              hipStream_t stream) {
  const float* initial    = (const float*)d_in[0];
  const float* transition = (const float*)d_in[1];
  const float* tmat       = (const float*)d_in[2];
  float* out = (float*)d_out;

  const int N  = in_sizes[0] / 2;           // 200000 emitters
  const int nf = (N > 0) ? (out_size / N) : 0;  // 500 frames
  if (N <= 0 || nf <= 0) return;

  // T threads total; each owns emitters t and t+T. T=131072 -> 2048 waves
  // = exactly 2 waves/SIMD across the chip.
  int T;
  if (N >= 131072) T = 131072;
  else T = ((N + 255) / 256) * 256;

  const int block = 256;
  const int grid = T / block;
  const size_t shmem = (size_t)(nf + 1) * sizeof(uint2);
  hipLaunchKernelGGL(markov_kernel, dim3(grid), dim3(block), shmem, stream,
                     initial, transition, tmat, out, N, nf, T);
}

// Round 3
// 281.274 us; speedup vs baseline: 1.7795x; 1.0005x over previous
//
#include <hip/hip_runtime.h>
#include <stdint.h>

// SimpleMarkovModel: 2-state Markov chain, 200000 emitters x 500 frames.
// Bit-exact JAX partitionable Threefry-2x32 (verified rounds 1-2, absmax 0).
//
// R3 structure:
//  - Prologue kernel writes the nf split subkeys (+1 zero pad) to d_ws.
//  - Main kernel: block=64 (1 wave), every wave runs TWO interleaved cipher
//    chains (emitters tid and tid+Th) -> stall-free in-order issue.
//  - Subkey read is uniform-indexed -> compiler emits s_load; whole key
//    schedule (k2, c1..c5) lands in SALU. Injections are v_add v,s,v.
//  - Thresholds pre-shifted: u < p  <=>  bits < (ceil(p*2^23) << 9).
//  - One v_cmp(s!=0) feeds both next-threshold select and the output value.
//  - Stores: uniform base (out + f*N, SGPR-advanced) + fixed lane offset.

#define ROTL32(x, d) __builtin_rotateleft32((x), (d))

__device__ __forceinline__ void tf2x32(uint32_t k0, uint32_t k1,
                                       uint32_t x0, uint32_t x1,
                                       uint32_t& o0, uint32_t& o1) {
  const uint32_t k2 = k0 ^ k1 ^ 0x1BD11BDAu;
  x0 += k0; x1 += k1;
#define TF_R(d) { x0 += x1; x1 = ROTL32(x1, d) ^ x0; }
  TF_R(13) TF_R(15) TF_R(26) TF_R(6)
  x0 += k1; x1 += k2 + 1u;
  TF_R(17) TF_R(29) TF_R(16) TF_R(24)
  x0 += k2; x1 += k0 + 2u;
  TF_R(13) TF_R(15) TF_R(26) TF_R(6)
  x0 += k0; x1 += k1 + 3u;
  TF_R(17) TF_R(29) TF_R(16) TF_R(24)
  x0 += k1; x1 += k2 + 4u;
  TF_R(13) TF_R(15) TF_R(26) TF_R(6)
  x0 += k2; x1 += k0 + 5u;
#undef TF_R
  o0 = x0; o1 = x1;
}

__global__ void subkeys_kernel(uint2* __restrict__ ks, int nf) {
  const int f = blockIdx.x * blockDim.x + threadIdx.x;
  if (f < nf) {
    uint32_t a, b;
    tf2x32(0u, 42u, 0u, (uint32_t)f, a, b);
    ks[f] = make_uint2(a, b);
  } else if (f == nf) {
    ks[f] = make_uint2(0u, 0u);  // pad so the prefetch never branches
  }
}

// The dual-chain frames loop, shared by the d_ws and LDS-fallback kernels.
__device__ __forceinline__ void run_dual(
    const uint2* __restrict__ ks, int nf, int N,
    int nA, int nB, bool hasB, uint32_t sA, uint32_t sB,
    uint32_t tsh0, uint32_t tsh1, uint32_t sw0, uint32_t sw1,
    float* __restrict__ out) {
  uint32_t thrA = sA ? tsh1 : tsh0;
  uint32_t thrB = sB ? tsh1 : tsh0;
  const uint32_t baseA = 2u * (uint32_t)nA;
  const uint32_t baseB = 2u * (uint32_t)nB;

  float* op = out;  // wave-uniform, advances by N per frame (SALU)
  uint2 ck = ks[0];
  for (int f = 0; f < nf; ++f) {
    const uint32_t k0 = ck.x, k1 = ck.y;
    ck = ks[f + 1];  // uniform prefetch (padded at f == nf-1)
    const uint32_t k2 = k0 ^ k1 ^ 0x1BD11BDAu;
    const uint32_t c1 = k2 + 1u, c2 = k0 + 2u, c3 = k1 + 3u,
                   c4 = k2 + 4u, c5 = k0 + 5u;

    uint32_t xa0 = k0, xa1 = baseA + sA + k1;   // v_add3
    uint32_t xb0 = k0, xb1 = baseB + sB + k1;

#define RND(d) { xa0 += xa1; xa1 = ROTL32(xa1, (d)) ^ xa0;   \
                 xb0 += xb1; xb1 = ROTL32(xb1, (d)) ^ xb0; }
    RND(13) RND(15) RND(26) RND(6)
    xa0 += k1; xa1 += c1; xb0 += k1; xb1 += c1;
    RND(17) RND(29) RND(16) RND(24)
    xa0 += k2; xa1 += c2; xb0 += k2; xb1 += c2;
    RND(13) RND(15) RND(26) RND(6)
    xa0 += k0; xa1 += c3; xb0 += k0; xb1 += c3;
    RND(17) RND(29) RND(16) RND(24)
    xa0 += k1; xa1 += c4; xb0 += k1; xb1 += c4;
    RND(13) RND(15) RND(26) RND(6)
    xa0 += k2; xa1 += c5; xb0 += k2; xb1 += c5;
#undef RND

    const uint32_t ra = xa0 ^ xa1;
    const uint32_t rb = xb0 ^ xb1;
    sA ^= (ra < thrA) ? sw1 : sw0;
    sB ^= (rb < thrB) ? sw1 : sw0;
    // one cmp(s!=0) feeds both selects below (compiler CSEs the condition)
    thrA = sA ? tsh1 : tsh0;
    thrB = sB ? tsh1 : tsh0;
    op[nA] = sA ? 0.0f : 1.0f;
    if (hasB) op[nB] = sB ? 0.0f : 1.0f;
    op += N;
  }
}

__device__ __forceinline__ void markov_body(
    const float* __restrict__ initial, const float* __restrict__ transition,
    const float* __restrict__ tmat, const uint2* __restrict__ ks,
    float* __restrict__ out, int N, int nf, int Th) {
  const int tid = blockIdx.x * blockDim.x + threadIdx.x;
  if (tid >= N) return;  // tiny-N guard
  const int nA = tid;
  const int nB = tid + Th;
  const bool hasB = (nB < N);

  // u < p  <=>  bits < (ceil(p*2^23) << 9); clamp guards p ~ 1.0.
  const uint64_t t0w = ((uint64_t)(uint32_t)ceilf(transition[1] * 8388608.0f)) << 9;
  const uint64_t t1w = ((uint64_t)(uint32_t)ceilf(transition[3] * 8388608.0f)) << 9;
  const uint32_t tsh0 = (t0w > 0xFFFFFFFFull) ? 0xFFFFFFFFu : (uint32_t)t0w;
  const uint32_t tsh1 = (t1w > 0xFFFFFFFFull) ? 0xFFFFFFFFu : (uint32_t)t1w;
  const uint32_t sw0 = (tmat[1] != 0.0f) ? 1u : 0u;  // matrix 0 swaps?
  const uint32_t sw1 = (tmat[5] != 0.0f) ? 1u : 0u;  // matrix 1 swaps?

  const uint32_t sA = (initial[2 * nA] != 0.0f) ? 0u : 1u;
  const uint32_t sB = hasB ? ((initial[2 * nB] != 0.0f) ? 0u : 1u) : 0u;

  run_dual(ks, nf, N, nA, nB, hasB, sA, sB, tsh0, tsh1, sw0, sw1, out);
}

__global__ __launch_bounds__(64) void markov_kernel(
    const float* __restrict__ initial, const float* __restrict__ transition,
    const float* __restrict__ tmat, const uint2* __restrict__ ks,
    float* __restrict__ out, int N, int nf, int Th) {
  markov_body(initial, transition, tmat, ks, out, N, nf, Th);
}

// Fallback if d_ws is too small: compute subkeys into LDS per block.
__global__ __launch_bounds__(64) void markov_kernel_lds(
    const float* __restrict__ initial, const float* __restrict__ transition,
    const float* __restrict__ tmat, float* __restrict__ out,
    int N, int nf, int Th) {
  extern __shared__ uint2 kf[];
  for (int f = threadIdx.x; f <= nf; f += blockDim.x) {
    uint2 k = make_uint2(0u, 0u);
    if (f < nf) {
      uint32_t a, b;
      tf2x32(0u, 42u, 0u, (uint32_t)f, a, b);
      k = make_uint2(a, b);
    }
    kf[f] = k;
  }
  __syncthreads();
  markov_body(initial, transition, tmat, kf, out, N, nf, Th);
}

extern "C" void kernel_launch(void* const* d_in, const int* in_sizes, int n_in,
                              void* d_out, int out_size, void* d_ws, size_t ws_size,
                              hipStream_t stream) {
  const float* initial    = (const float*)d_in[0];
  const float* transition = (const float*)d_in[1];
  const float* tmat       = (const float*)d_in[2];
  float* out = (float*)d_out;

  const int N  = in_sizes[0] / 2;               // 200000 emitters
  const int nf = (N > 0) ? (out_size / N) : 0;  // 500 frames
  if (N <= 0 || nf <= 0) return;

  // Every wave dual-chain: thread t owns emitters t and t+Th.
  const int Th = (((N + 1) / 2) + 63) & ~63;    // 100032 for N=200000
  const int grid = Th / 64;                     // 1563 waves

  const size_t need = (size_t)(nf + 1) * sizeof(uint2);
  if (ws_size >= need) {
    uint2* ks = (uint2*)d_ws;
    subkeys_kernel<<<(nf + 1 + 255) / 256, 256, 0, stream>>>(ks, nf);
    markov_kernel<<<grid, 64, 0, stream>>>(initial, transition, tmat, ks,
                                           out, N, nf, Th);
  } else {
    markov_kernel_lds<<<grid, 64, need, stream>>>(initial, transition, tmat,
                                                  out, N, nf, Th);
  }
}

// Round 4
// 276.396 us; speedup vs baseline: 1.8109x; 1.0176x over previous
//
#include <hip/hip_runtime.h>
#include <stdint.h>

// SimpleMarkovModel: 2-state Markov chain, 200000 emitters x 500 frames.
// Bit-exact JAX partitionable Threefry-2x32 (verified rounds 1-3, absmax 0).
//
// R4 changes (attacking the ~2x gap between measured 294us and the ~140us
// issue-bound model):
//  - Rotates via __builtin_amdgcn_alignbit(x,x,32-d): guaranteed single
//    v_alignbit_b32 (if rotateleft32 was lowering to shl+shr+or, that alone
//    was +80 VALU/frame).
//  - Subkeys consumed in groups of 4 frames as 2x uint4 scalar loads,
//    software double-buffered: loads for group g+1 issue before group g's
//    ~1300-cycle compute -> SMEM latency structurally hidden even at
//    1-2 waves/SIMD. Table padded by 2 groups so the hot loop never branches
//    on load range.

#define ROTL32(x, d) __builtin_amdgcn_alignbit((x), (x), 32 - (d))

__device__ __forceinline__ void tf2x32(uint32_t k0, uint32_t k1,
                                       uint32_t x0, uint32_t x1,
                                       uint32_t& o0, uint32_t& o1) {
  const uint32_t k2 = k0 ^ k1 ^ 0x1BD11BDAu;
  x0 += k0; x1 += k1;
#define TF_R(d) { x0 += x1; x1 = ROTL32(x1, d) ^ x0; }
  TF_R(13) TF_R(15) TF_R(26) TF_R(6)
  x0 += k1; x1 += k2 + 1u;
  TF_R(17) TF_R(29) TF_R(16) TF_R(24)
  x0 += k2; x1 += k0 + 2u;
  TF_R(13) TF_R(15) TF_R(26) TF_R(6)
  x0 += k0; x1 += k1 + 3u;
  TF_R(17) TF_R(29) TF_R(16) TF_R(24)
  x0 += k1; x1 += k2 + 4u;
  TF_R(13) TF_R(15) TF_R(26) TF_R(6)
  x0 += k2; x1 += k0 + 5u;
#undef TF_R
  o0 = x0; o1 = x1;
}

// Subkey table: keys[f] = threefry2x32((0,42),(0,f)); zero-padded to cap.
__global__ void subkeys_kernel(uint2* __restrict__ ks, int nf, int cap) {
  const int f = blockIdx.x * blockDim.x + threadIdx.x;
  if (f < nf) {
    uint32_t a, b;
    tf2x32(0u, 42u, 0u, (uint32_t)f, a, b);
    ks[f] = make_uint2(a, b);
  } else if (f < cap) {
    ks[f] = make_uint2(0u, 0u);
  }
}

struct ChainState {
  uint32_t s;     // 0 = "on" (output 1.0)
  uint32_t thr;   // pre-selected, pre-shifted threshold for this frame
  uint32_t base;  // 2n
};

// One frame for two interleaved chains. k0/k1 wave-uniform (SGPR).
__device__ __forceinline__ void do_frame(
    uint32_t k0, uint32_t k1, ChainState& A, ChainState& B,
    uint32_t tsh0, uint32_t tsh1, uint32_t sw0, uint32_t sw1,
    float* __restrict__ op, int nA, int nB, bool hasB) {
  const uint32_t k2 = k0 ^ k1 ^ 0x1BD11BDAu;
  const uint32_t c1 = k2 + 1u, c2 = k0 + 2u, c3 = k1 + 3u,
                 c4 = k2 + 4u, c5 = k0 + 5u;

  uint32_t xa0 = k0, xa1 = A.base + A.s + k1;   // v_add3
  uint32_t xb0 = k0, xb1 = B.base + B.s + k1;

#define RND(d) { xa0 += xa1; xa1 = ROTL32(xa1, (d)) ^ xa0;   \
                 xb0 += xb1; xb1 = ROTL32(xb1, (d)) ^ xb0; }
  RND(13) RND(15) RND(26) RND(6)
  xa0 += k1; xa1 += c1; xb0 += k1; xb1 += c1;
  RND(17) RND(29) RND(16) RND(24)
  xa0 += k2; xa1 += c2; xb0 += k2; xb1 += c2;
  RND(13) RND(15) RND(26) RND(6)
  xa0 += k0; xa1 += c3; xb0 += k0; xb1 += c3;
  RND(17) RND(29) RND(16) RND(24)
  xa0 += k1; xa1 += c4; xb0 += k1; xb1 += c4;
  RND(13) RND(15) RND(26) RND(6)
  xa0 += k2; xa1 += c5; xb0 += k2; xb1 += c5;
#undef RND

  const uint32_t ra = xa0 ^ xa1;
  const uint32_t rb = xb0 ^ xb1;
  A.s ^= (ra < A.thr) ? sw1 : sw0;
  B.s ^= (rb < B.thr) ? sw1 : sw0;
  const bool zA = (A.s != 0);
  const bool zB = (B.s != 0);
  A.thr = zA ? tsh1 : tsh0;
  B.thr = zB ? tsh1 : tsh0;
  op[nA] = zA ? 0.0f : 1.0f;
  if (hasB) op[nB] = zB ? 0.0f : 1.0f;
}

__device__ __forceinline__ void markov_body(
    const float* __restrict__ initial, const float* __restrict__ transition,
    const float* __restrict__ tmat, const uint2* __restrict__ ks,
    float* __restrict__ out, int N, int nf, int Th) {
  const int tid = blockIdx.x * blockDim.x + threadIdx.x;
  if (tid >= N) return;
  const int nA = tid;
  const int nB = tid + Th;
  const bool hasB = (nB < N);   // wave-uniform (Th is 64-aligned)

  // u < p  <=>  bits < (ceil(p*2^23) << 9); clamp guards p ~ 1.0.
  const uint64_t t0w = ((uint64_t)(uint32_t)ceilf(transition[1] * 8388608.0f)) << 9;
  const uint64_t t1w = ((uint64_t)(uint32_t)ceilf(transition[3] * 8388608.0f)) << 9;
  const uint32_t tsh0 = (t0w > 0xFFFFFFFFull) ? 0xFFFFFFFFu : (uint32_t)t0w;
  const uint32_t tsh1 = (t1w > 0xFFFFFFFFull) ? 0xFFFFFFFFu : (uint32_t)t1w;
  const uint32_t sw0 = (tmat[1] != 0.0f) ? 1u : 0u;  // matrix 0 swaps?
  const uint32_t sw1 = (tmat[5] != 0.0f) ? 1u : 0u;  // matrix 1 swaps?

  ChainState A, B;
  A.s = (initial[2 * nA] != 0.0f) ? 0u : 1u;
  B.s = hasB ? ((initial[2 * nB] != 0.0f) ? 0u : 1u) : 0u;
  A.thr = A.s ? tsh1 : tsh0;
  B.thr = B.s ? tsh1 : tsh0;
  A.base = 2u * (uint32_t)nA;
  B.base = 2u * (uint32_t)nB;

  float* op = out;                     // wave-uniform, advances by N/frame
  const uint4* kq = (const uint4*)ks;  // 2 subkeys per uint4

  const int ng = nf / 4;               // full 4-frame groups
  uint4 a0 = kq[0], a1 = kq[1];        // current group's 4 subkeys
  for (int g = 0; g < ng; ++g) {
    const uint4 b0 = kq[2 * g + 2];    // next group (pad guarantees valid)
    const uint4 b1 = kq[2 * g + 3];
    do_frame(a0.x, a0.y, A, B, tsh0, tsh1, sw0, sw1, op, nA, nB, hasB); op += N;
    do_frame(a0.z, a0.w, A, B, tsh0, tsh1, sw0, sw1, op, nA, nB, hasB); op += N;
    do_frame(a1.x, a1.y, A, B, tsh0, tsh1, sw0, sw1, op, nA, nB, hasB); op += N;
    do_frame(a1.z, a1.w, A, B, tsh0, tsh1, sw0, sw1, op, nA, nB, hasB); op += N;
    a0 = b0; a1 = b1;
  }
  for (int f = ng * 4; f < nf; ++f) {  // tail (empty when nf % 4 == 0)
    const uint2 k = ks[f];
    do_frame(k.x, k.y, A, B, tsh0, tsh1, sw0, sw1, op, nA, nB, hasB); op += N;
  }
}

__global__ __launch_bounds__(64) void markov_kernel(
    const float* __restrict__ initial, const float* __restrict__ transition,
    const float* __restrict__ tmat, const uint2* __restrict__ ks,
    float* __restrict__ out, int N, int nf, int Th) {
  markov_body(initial, transition, tmat, ks, out, N, nf, Th);
}

// Fallback if d_ws is too small: subkeys in LDS (same padded layout).
__global__ __launch_bounds__(64) void markov_kernel_lds(
    const float* __restrict__ initial, const float* __restrict__ transition,
    const float* __restrict__ tmat, float* __restrict__ out,
    int N, int nf, int Th, int cap) {
  extern __shared__ uint2 kf[];
  for (int f = threadIdx.x; f < cap; f += blockDim.x) {
    uint2 k = make_uint2(0u, 0u);
    if (f < nf) {
      uint32_t a, b;
      tf2x32(0u, 42u, 0u, (uint32_t)f, a, b);
      k = make_uint2(a, b);
    }
    kf[f] = k;
  }
  __syncthreads();
  markov_body(initial, transition, tmat, kf, out, N, nf, Th);
}

extern "C" void kernel_launch(void* const* d_in, const int* in_sizes, int n_in,
                              void* d_out, int out_size, void* d_ws, size_t ws_size,
                              hipStream_t stream) {
  const float* initial    = (const float*)d_in[0];
  const float* transition = (const float*)d_in[1];
  const float* tmat       = (const float*)d_in[2];
  float* out = (float*)d_out;

  const int N  = in_sizes[0] / 2;               // 200000 emitters
  const int nf = (N > 0) ? (out_size / N) : 0;  // 500 frames
  if (N <= 0 || nf <= 0) return;

  // Every wave dual-chain: thread t owns emitters t and t+Th.
  const int Th = (((N + 1) / 2) + 63) & ~63;    // 100032 for N=200000
  const int grid = Th / 64;                     // 1563 waves

  const int cap = (nf / 4 + 2) * 4;             // padded subkey count
  const size_t need = (size_t)cap * sizeof(uint2);
  if (ws_size >= need) {
    uint2* ks = (uint2*)d_ws;
    subkeys_kernel<<<(cap + 255) / 256, 256, 0, stream>>>(ks, nf, cap);
    markov_kernel<<<grid, 64, 0, stream>>>(initial, transition, tmat, ks,
                                           out, N, nf, Th);
  } else {
    markov_kernel_lds<<<grid, 64, need, stream>>>(initial, transition, tmat,
                                                  out, N, nf, Th, cap);
  }
}